// Round 7
// baseline (277.463 us; speedup 1.0000x reference)
//
#include <hip/hip_runtime.h>
#include <hip/hip_bf16.h>

// SelfAttention1d  B=16, C=512, L=1024
// R7: R6 algebra kept (S = hnT·G·hn, G=scale·Wq^T·Wk precomputed; fused V/T1).
//     FIX: G was a 16-block GEMM -> pure latency-bound (~25-30us on critical
//     path). Now split-K: 8 slices x K=64 (128 blocks) -> fp32 partials ->
//     reduce+cast kernel. g2 GEMV unrolled 8x for load ILP.

#define BB 16
#define CC 512
#define LL 1024
#define SCALE 0.04419417382415922f

typedef __bf16 bf16x8 __attribute__((ext_vector_type(8)));
typedef float  f32x4  __attribute__((ext_vector_type(4)));

__device__ inline unsigned short bf16_bits(float f) {
  __hip_bfloat16 h = __float2bfloat16(f);
  return __builtin_bit_cast(unsigned short, h);
}
__device__ inline float bits_lo(unsigned int u) {
  return __builtin_bit_cast(float, u << 16);
}
__device__ inline float bits_hi(unsigned int u) {
  return __builtin_bit_cast(float, u & 0xffff0000u);
}

// ---------------- BN stats: one block per channel ----------------
__global__ __launch_bounds__(256) void bn_stats(
    const float* __restrict__ x, const float* __restrict__ gamma,
    const float* __restrict__ beta, float* __restrict__ scl,
    float* __restrict__ sft) {
  int c = blockIdx.x;
  int t = threadIdx.x;
  float s = 0.f, s2 = 0.f;
  for (int b = 0; b < BB; ++b) {
    float4 v = ((const float4*)(x + ((size_t)(b * CC + c)) * LL))[t];
    s  += v.x + v.y + v.z + v.w;
    s2 += v.x * v.x + v.y * v.y + v.z * v.z + v.w * v.w;
  }
  for (int m = 32; m; m >>= 1) { s += __shfl_xor(s, m, 64); s2 += __shfl_xor(s2, m, 64); }
  __shared__ float rs[4], rs2[4];
  int wave = t >> 6, lane = t & 63;
  if (lane == 0) { rs[wave] = s; rs2[wave] = s2; }
  __syncthreads();
  if (t == 0) {
    float S  = rs[0] + rs[1] + rs[2] + rs[3];
    float S2 = rs2[0] + rs2[1] + rs2[2] + rs2[3];
    float mean = S * (1.f / 16384.f);
    float var  = S2 * (1.f / 16384.f) - mean * mean;
    float sc = gamma[c] * rsqrtf(var + 1e-5f);
    scl[c] = sc;
    sft[c] = beta[c] - mean * sc;
  }
}

// ---- cast/transpose: WqT,WkT (transposed bf16), Wv->A'[0:512), Wp natural;
//      blockIdx.y==4 computes g2[c] = sum_o Wk[o][c]*bq[o] (fp32) ----------
__global__ __launch_bounds__(256) void cast_t(
    const float* __restrict__ Wq, const float* __restrict__ Wk,
    const float* __restrict__ Wv, const float* __restrict__ Wp,
    const float* __restrict__ bq,
    __hip_bfloat16* __restrict__ WqT, __hip_bfloat16* __restrict__ WkT,
    __hip_bfloat16* __restrict__ Avt1, __hip_bfloat16* __restrict__ Wpb,
    float* __restrict__ g2) {
  int m = blockIdx.y;
  int t = threadIdx.x;
  if (m < 2) {
    const float* src = m == 0 ? Wq : Wk;
    __hip_bfloat16* dst = m == 0 ? WqT : WkT;
    __shared__ float tile[32][33];
    int o0 = (blockIdx.x >> 4) * 32, a0 = (blockIdx.x & 15) * 32;
#pragma unroll
    for (int i = 0; i < 4; ++i) {
      int idx = t + i * 256;
      int oo = idx >> 5, aa = idx & 31;
      tile[oo][aa] = src[(size_t)(o0 + oo) * 512 + a0 + aa];
    }
    __syncthreads();
#pragma unroll
    for (int i = 0; i < 2; ++i) {
      int idx = t + i * 256;
      int aa = idx >> 4, oo = (idx & 15) * 2;
      ushort2 o;
      o.x = bf16_bits(tile[oo][aa]);
      o.y = bf16_bits(tile[oo + 1][aa]);
      *(ushort2*)(dst + (size_t)(a0 + aa) * 512 + o0 + oo) = o;
    }
  } else if (m < 4) {
    const float* src = m == 2 ? Wv : Wp;
    __hip_bfloat16* dst = m == 2 ? Avt1 : Wpb;
    int i = blockIdx.x * 1024 + t * 4;
    float4 v = *(const float4*)(src + i);
    ushort4 o;
    o.x = bf16_bits(v.x); o.y = bf16_bits(v.y);
    o.z = bf16_bits(v.z); o.w = bf16_bits(v.w);
    *(ushort4*)(dst + i) = o;
  } else {
    if (blockIdx.x >= 2) return;
    int c = blockIdx.x * 256 + t;
    float acc = 0.f;
#pragma unroll 8
    for (int o = 0; o < 512; ++o) acc += Wk[(size_t)o * 512 + c] * bq[o];
    g2[c] = acc;
  }
}

// ---------------- normalize + transpose: x [B][C][L] -> hnT [B][L][C] bf16 ----
__global__ __launch_bounds__(256) void norm_t(
    const float* __restrict__ x, const float* __restrict__ scl,
    const float* __restrict__ sft, __hip_bfloat16* __restrict__ hnT) {
  __shared__ float tile[32][33];
  int l0 = blockIdx.x * 32, c0 = blockIdx.y * 32, b = blockIdx.z;
  int t = threadIdx.x;
#pragma unroll
  for (int i = 0; i < 4; ++i) {
    int idx = t + i * 256;
    int cc = idx >> 5, ll = idx & 31;
    tile[cc][ll] = x[((size_t)(b * CC + c0 + cc)) * LL + l0 + ll];
  }
  __syncthreads();
#pragma unroll
  for (int i = 0; i < 2; ++i) {
    int idx = t + i * 256;
    int ll = idx >> 4, cc = (idx & 15) * 2;
    float v0 = tile[cc][ll] * scl[c0 + cc] + sft[c0 + cc];
    float v1 = tile[cc + 1][ll] * scl[c0 + cc + 1] + sft[c0 + cc + 1];
    ushort2 o; o.x = bf16_bits(v0); o.y = bf16_bits(v1);
    *(ushort2*)(hnT + ((size_t)(b * LL + l0 + ll)) * CC + c0 + cc) = o;
  }
}

// ---------------- w GEMV: w[row] = hnT[row]·g2, one row per wave --------------
__global__ __launch_bounds__(256) void w_gemv(
    const __hip_bfloat16* __restrict__ hnT, const float* __restrict__ g2,
    float* __restrict__ w) {
  int wave = threadIdx.x >> 6, lane = threadIdx.x & 63;
  size_t row = (size_t)blockIdx.x * 4 + wave;
  bf16x8 h = *(const bf16x8*)(hnT + row * 512 + lane * 8);
  const float* g = g2 + lane * 8;
  float s = 0.f;
#pragma unroll
  for (int e = 0; e < 8; ++e) s += (float)h[e] * g[e];
  for (int m = 32; m; m >>= 1) s += __shfl_xor(s, m, 64);
  if (lane == 0) w[row] = s;
}

// ---------------- softmax with +w: one row per wave, bf16 in place ------------
__global__ __launch_bounds__(256) void softmax_w(
    __hip_bfloat16* __restrict__ S, const float* __restrict__ w) {
  int wave = threadIdx.x >> 6, lane = threadIdx.x & 63;
  size_t row = (size_t)blockIdx.x * 4 + wave;
  uint4* p = (uint4*)(S + row * 1024);
  uint4 r0 = p[lane * 2], r1 = p[lane * 2 + 1];
  const float4* wp = (const float4*)(w + (row >> 10) * 1024 + lane * 16);
  float4 w0 = wp[0], w1 = wp[1], w2 = wp[2], w3 = wp[3];
  float wv[16] = {w0.x, w0.y, w0.z, w0.w, w1.x, w1.y, w1.z, w1.w,
                  w2.x, w2.y, w2.z, w2.w, w3.x, w3.y, w3.z, w3.w};
  float f[16];
  unsigned int ww[8] = {r0.x, r0.y, r0.z, r0.w, r1.x, r1.y, r1.z, r1.w};
#pragma unroll
  for (int i = 0; i < 8; ++i) {
    f[2 * i] = bits_lo(ww[i]) + wv[2 * i];
    f[2 * i + 1] = bits_hi(ww[i]) + wv[2 * i + 1];
  }
  float mx = f[0];
#pragma unroll
  for (int i = 1; i < 16; ++i) mx = fmaxf(mx, f[i]);
  for (int m = 32; m; m >>= 1) mx = fmaxf(mx, __shfl_xor(mx, m, 64));
  float s = 0.f;
#pragma unroll
  for (int i = 0; i < 16; ++i) { f[i] = __expf(f[i] - mx); s += f[i]; }
  for (int m = 32; m; m >>= 1) s += __shfl_xor(s, m, 64);
  float inv = 1.f / s;
  unsigned int ow[8];
#pragma unroll
  for (int i = 0; i < 8; ++i) {
    unsigned int lo = bf16_bits(f[2 * i] * inv);
    unsigned int hi = bf16_bits(f[2 * i + 1] * inv);
    ow[i] = lo | (hi << 16);
  }
  uint4 o0 = {ow[0], ow[1], ow[2], ow[3]}, o1 = {ow[4], ow[5], ow[6], ow[7]};
  p[lane * 2] = o0; p[lane * 2 + 1] = o1;
}

// ---------------- GEMM core (R3-proven): acc += A[128xK] * B[128xK]^T ---------
__device__ inline void glds(const __hip_bfloat16* g, __hip_bfloat16* l) {
  __builtin_amdgcn_global_load_lds(
      (__attribute__((address_space(1))) void*)(void*)g,
      (__attribute__((address_space(3))) void*)l, 16, 0, 0);
}

__device__ __forceinline__ void gemm_core(
    const __hip_bfloat16* __restrict__ A, int lda,
    const __hip_bfloat16* __restrict__ B, int ldb, int K,
    __hip_bfloat16* sA, __hip_bfloat16* sB, f32x4 (&acc)[4][4]) {
  const int tid = threadIdx.x;
  const int wave = tid >> 6, lane = tid & 63;
  const int wm = (wave >> 1) * 64, wn = (wave & 1) * 64;
  const int row0 = tid >> 2;
  const int ke0 = (((tid & 3) ^ ((tid >> 3) & 3)) * 8);
  const int fr = lane & 15;
  const int q = lane >> 4;
  const int colA = ((q ^ ((fr >> 1) & 3)) * 8);
  for (int k0 = 0; k0 < K; k0 += 32) {
    __syncthreads();
#pragma unroll
    for (int it = 0; it < 2; ++it) {
      const __hip_bfloat16* ga = A + (size_t)(it * 64 + row0) * lda + (k0 + ke0);
      const __hip_bfloat16* gb = B + (size_t)(it * 64 + row0) * ldb + (k0 + ke0);
      glds(ga, sA + (it * 256 + wave * 64) * 8);
      glds(gb, sB + (it * 256 + wave * 64) * 8);
    }
    __syncthreads();
    bf16x8 af[4], bfr[4];
#pragma unroll
    for (int i = 0; i < 4; ++i) {
      af[i]  = *(const bf16x8*)(sA + (wm + i * 16 + fr) * 32 + colA);
      bfr[i] = *(const bf16x8*)(sB + (wn + i * 16 + fr) * 32 + colA);
    }
#pragma unroll
    for (int i = 0; i < 4; ++i)
#pragma unroll
      for (int j = 0; j < 4; ++j)
        acc[i][j] = __builtin_amdgcn_mfma_f32_16x16x32_bf16(af[i], bfr[j], acc[i][j], 0, 0, 0);
  }
}

// ---- split-K G partials: grid (4,4,8); slice s covers k in [s*64,s*64+64) ----
// D[n=a][m=b] fp32 into Gpart + s*262144 (packed float4 along b).
__global__ __launch_bounds__(256, 3) void gemm_g_split(
    const __hip_bfloat16* __restrict__ WkT, const __hip_bfloat16* __restrict__ WqT,
    float* __restrict__ Gpart) {
  __shared__ __align__(16) __hip_bfloat16 sA[128 * 32];
  __shared__ __align__(16) __hip_bfloat16 sB[128 * 32];
  const int s = blockIdx.z;
  const int m0 = blockIdx.y * 128, n0 = blockIdx.x * 128;
  f32x4 acc[4][4] = {};
  gemm_core(WkT + (size_t)m0 * 512 + s * 64, 512,
            WqT + (size_t)n0 * 512 + s * 64, 512, 64, sA, sB, acc);
  const int lane = threadIdx.x & 63, wave = threadIdx.x >> 6;
  const int wm = (wave >> 1) * 64, wn = (wave & 1) * 64;
  const int crow = (lane >> 4) * 4, ccol = lane & 15;
  float* D = Gpart + (size_t)s * 262144;
#pragma unroll
  for (int j = 0; j < 4; ++j) {
    int ng = n0 + wn + j * 16 + ccol;
#pragma unroll
    for (int i = 0; i < 4; ++i) {
      int mg = m0 + wm + i * 16 + crow;
      float4 o = {acc[i][j][0], acc[i][j][1], acc[i][j][2], acc[i][j][3]};
      *(float4*)(D + (size_t)ng * 512 + mg) = o;
    }
  }
}

// ---- reduce 8 partials -> Gm bf16 (with SCALE) -------------------------------
__global__ __launch_bounds__(256) void reduce_g(
    const float* __restrict__ Gpart, __hip_bfloat16* __restrict__ Gm) {
  int idx = (blockIdx.x * 256 + threadIdx.x) * 4;
  float4 a = {0.f, 0.f, 0.f, 0.f};
#pragma unroll
  for (int s = 0; s < 8; ++s) {
    float4 v = *(const float4*)(Gpart + (size_t)s * 262144 + idx);
    a.x += v.x; a.y += v.y; a.z += v.z; a.w += v.w;
  }
  ushort4 o;
  o.x = bf16_bits(a.x * SCALE); o.y = bf16_bits(a.y * SCALE);
  o.z = bf16_bits(a.z * SCALE); o.w = bf16_bits(a.w * SCALE);
  *(ushort4*)(Gm + idx) = o;
}

// ---------------- generic GEMM, bf16 packed T-store D[n][m] (+bias[n]) --------
template <bool BIAS>
__global__ __launch_bounds__(256, 3) void gemm_bf16t(
    const __hip_bfloat16* __restrict__ A, int lda, size_t strideA,
    const __hip_bfloat16* __restrict__ B, int ldb, size_t strideB,
    __hip_bfloat16* __restrict__ D, int ldd, size_t strideD,
    const float* __restrict__ bias, float scale, int K) {
  __shared__ __align__(16) __hip_bfloat16 sA[128 * 32];
  __shared__ __align__(16) __hip_bfloat16 sB[128 * 32];
  const int bat = blockIdx.z;
  const int m0 = blockIdx.y * 128, n0 = blockIdx.x * 128;
  f32x4 acc[4][4] = {};
  gemm_core(A + (size_t)bat * strideA + (size_t)m0 * lda, lda,
            B + (size_t)bat * strideB + (size_t)n0 * ldb, ldb, K, sA, sB, acc);
  const int lane = threadIdx.x & 63, wave = threadIdx.x >> 6;
  const int wm = (wave >> 1) * 64, wn = (wave & 1) * 64;
  const int crow = (lane >> 4) * 4, ccol = lane & 15;
  __hip_bfloat16* Db = D + (size_t)bat * strideD;
#pragma unroll
  for (int j = 0; j < 4; ++j) {
    int ng = n0 + wn + j * 16 + ccol;
    float bn = BIAS ? bias[ng] : 0.f;
#pragma unroll
    for (int i = 0; i < 4; ++i) {
      int mg = m0 + wm + i * 16 + crow;
      ushort4 o;
      o.x = bf16_bits(acc[i][j][0] * scale + bn);
      o.y = bf16_bits(acc[i][j][1] * scale + bn);
      o.z = bf16_bits(acc[i][j][2] * scale + bn);
      o.w = bf16_bits(acc[i][j][3] * scale + bn);
      *(ushort4*)(Db + (size_t)ng * ldd + mg) = o;
    }
  }
}

// ---- fused V/T1: A'=[Wv;G] (1024x512) x hnT -> vN [c][j] natural (+bv),
//      T1T [j][a] packed T-store ----------------------------------------------
__global__ __launch_bounds__(256, 3) void gemm_vt1(
    const __hip_bfloat16* __restrict__ Ap, const __hip_bfloat16* __restrict__ hnT,
    __hip_bfloat16* __restrict__ vN, __hip_bfloat16* __restrict__ T1T,
    const float* __restrict__ bv) {
  __shared__ __align__(16) __hip_bfloat16 sA[128 * 32];
  __shared__ __align__(16) __hip_bfloat16 sB[128 * 32];
  const int bat = blockIdx.z;
  const int m0 = blockIdx.y * 128, n0 = blockIdx.x * 128;
  f32x4 acc[4][4] = {};
  gemm_core(Ap + (size_t)m0 * 512, 512,
            hnT + (size_t)bat * LL * CC + (size_t)n0 * 512, 512, 512, sA, sB, acc);
  const int lane = threadIdx.x & 63, wave = threadIdx.x >> 6;
  const int wm = (wave >> 1) * 64, wn = (wave & 1) * 64;
  const int crow = (lane >> 4) * 4, ccol = lane & 15;
  const int mloc0 = m0 & 511;
  if (m0 < 512) {
    __hip_bfloat16* D = vN + (size_t)bat * CC * LL;
#pragma unroll
    for (int i = 0; i < 4; ++i) {
      int mg = mloc0 + wm + i * 16 + crow;
      float bv4[4];
#pragma unroll
      for (int r = 0; r < 4; ++r) bv4[r] = bv[mg + r];
#pragma unroll
      for (int j = 0; j < 4; ++j) {
        int ng = n0 + wn + j * 16 + ccol;
#pragma unroll
        for (int r = 0; r < 4; ++r)
          D[(size_t)(mg + r) * 1024 + ng] = __float2bfloat16(acc[i][j][r] + bv4[r]);
      }
    }
  } else {
    __hip_bfloat16* D = T1T + (size_t)bat * LL * CC;
#pragma unroll
    for (int j = 0; j < 4; ++j) {
      int ng = n0 + wn + j * 16 + ccol;
#pragma unroll
      for (int i = 0; i < 4; ++i) {
        int mg = mloc0 + wm + i * 16 + crow;
        ushort4 o;
        o.x = bf16_bits(acc[i][j][0]);
        o.y = bf16_bits(acc[i][j][1]);
        o.z = bf16_bits(acc[i][j][2]);
        o.w = bf16_bits(acc[i][j][3]);
        *(ushort4*)(D + (size_t)ng * 512 + mg) = o;
      }
    }
  }
}

// ---------------- proj GEMM, fp32 T-store: D[n][m] = acc + bias[n] + resid ----
__global__ __launch_bounds__(256, 3) void gemm_f32t(
    const __hip_bfloat16* __restrict__ A, int lda, size_t strideA,
    const __hip_bfloat16* __restrict__ B, int ldb,
    float* __restrict__ D, int ldd, size_t strideD,
    const float* __restrict__ bias, const float* __restrict__ resid, int K) {
  __shared__ __align__(16) __hip_bfloat16 sA[128 * 32];
  __shared__ __align__(16) __hip_bfloat16 sB[128 * 32];
  const int bat = blockIdx.z;
  const int m0 = blockIdx.y * 128, n0 = blockIdx.x * 128;
  f32x4 acc[4][4] = {};
  gemm_core(A + (size_t)bat * strideA + (size_t)m0 * lda, lda,
            B + (size_t)n0 * ldb, ldb, K, sA, sB, acc);
  const int lane = threadIdx.x & 63, wave = threadIdx.x >> 6;
  const int wm = (wave >> 1) * 64, wn = (wave & 1) * 64;
  const int crow = (lane >> 4) * 4, ccol = lane & 15;
  float* Db = D + (size_t)bat * strideD;
  const float* Rb = resid + (size_t)bat * strideD;
#pragma unroll
  for (int j = 0; j < 4; ++j) {
    int ng = n0 + wn + j * 16 + ccol;
    float bn = bias[ng];
#pragma unroll
    for (int i = 0; i < 4; ++i) {
      int mg = m0 + wm + i * 16 + crow;
      float4 r = *(const float4*)(Rb + (size_t)ng * ldd + mg);
      float4 o;
      o.x = acc[i][j][0] + bn + r.x;
      o.y = acc[i][j][1] + bn + r.y;
      o.z = acc[i][j][2] + bn + r.z;
      o.w = acc[i][j][3] + bn + r.w;
      *(float4*)(Db + (size_t)ng * ldd + mg) = o;
    }
  }
}

extern "C" void kernel_launch(void* const* d_in, const int* in_sizes, int n_in,
                              void* d_out, int out_size, void* d_ws, size_t ws_size,
                              hipStream_t stream) {
  const float* x     = (const float*)d_in[0];
  const float* gamma = (const float*)d_in[1];
  const float* beta  = (const float*)d_in[2];
  const float* Wq    = (const float*)d_in[3];
  const float* bq    = (const float*)d_in[4];
  const float* Wk    = (const float*)d_in[5];
  const float* bk    = (const float*)d_in[6];  // cancels in softmax (row-const)
  const float* Wv    = (const float*)d_in[7];
  const float* bv    = (const float*)d_in[8];
  const float* Wp    = (const float*)d_in[9];
  const float* bp    = (const float*)d_in[10];
  float* out = (float*)d_out;
  (void)bk;

  char* ws = (char*)d_ws;
  float* scl = (float*)ws;                      // 512
  float* sft = scl + 512;                       // 512
  float* g2  = sft + 512;                       // 512
  float* w   = g2 + 512;                        // 16384
  __hip_bfloat16* WqT  = (__hip_bfloat16*)(w + 16384);
  __hip_bfloat16* WkT  = WqT + 262144;
  __hip_bfloat16* Wpb  = WkT + 262144;
  __hip_bfloat16* Avt1 = Wpb + 262144;          // [Wv(512) ; G(512)] x 512
  __hip_bfloat16* Gm   = Avt1 + 262144;         // rows 512..1023 of A'
  float* Gpart = (float*)(Avt1 + 524288);       // 8 x 512x512 fp32 partials
  __hip_bfloat16* hnT  = (__hip_bfloat16*)(Gpart + 2097152);  // [B][L][C]
  __hip_bfloat16* T1T  = hnT + 8388608;         // [B][L][C]
  __hip_bfloat16* vN   = T1T + 8388608;         // [B][C][L]
  __hip_bfloat16* Sb   = vN + 8388608;          // [B][L][L]
  __hip_bfloat16* HT   = hnT;                   // reuse: hnT dead after S-gemm

  const size_t sLC = (size_t)LL * CC;
  const size_t sCL = (size_t)CC * LL;
  const size_t sLLb = (size_t)LL * LL;

  bn_stats<<<512, 256, 0, stream>>>(x, gamma, beta, scl, sft);
  cast_t<<<dim3(256, 5), 256, 0, stream>>>(Wq, Wk, Wv, Wp, bq,
                                           WqT, WkT, Avt1, Wpb, g2);
  // G = SCALE * Wq^T Wk, split-K(8x64) -> fp32 partials -> reduce+cast
  gemm_g_split<<<dim3(4, 4, 8), 256, 0, stream>>>(WkT, WqT, Gpart);
  reduce_g<<<256, 256, 0, stream>>>(Gpart, Gm);
  norm_t<<<dim3(32, 16, 16), 256, 0, stream>>>(x, scl, sft, hnT);
  // w[b][j] = hnT[b][j]·g2
  w_gemv<<<4096, 256, 0, stream>>>(hnT, g2, w);
  // V (natural, +bv) and T1T (packed) in one pass over hnT
  gemm_vt1<<<dim3(8, 8, 16), 256, 0, stream>>>(Avt1, hnT, vN, T1T, bv);
  // S[i][j] = sum_c T1T[j][c] * hnT[i][c]  (pre-scaled via G)
  gemm_bf16t<false><<<dim3(8, 8, 16), 256, 0, stream>>>(
      T1T, 512, sLC, hnT, 512, sLC, Sb, 1024, sLLb, nullptr, 1.f, 512);
  // P = softmax_j(S + w_j), in place
  softmax_w<<<4096, 256, 0, stream>>>(Sb, w);
  // HT[i][c] = sum_j vN[c][j] * P[i][j]
  gemm_bf16t<false><<<dim3(8, 4, 16), 256, 0, stream>>>(
      vN, 1024, sCL, Sb, 1024, sLLb, HT, 512, sLC, nullptr, 1.f, 1024);
  // out[o][i] = sum_c HT[i][c]*Wp[o][c] + bp[o] + x[o][i]
  gemm_f32t<<<dim3(4, 8, 16), 256, 0, stream>>>(
      HT, 512, sLC, Wpb, 512, out, 1024, sCL, bp, x, 512);
}

// Round 8
// 260.107 us; speedup vs baseline: 1.0667x; 1.0667x over previous
//
#include <hip/hip_runtime.h>
#include <hip/hip_bf16.h>

// SelfAttention1d  B=16, C=512, L=1024
// R8: dispatch-count war + BK=64.
//  - prep: ONE kernel = bn_stats + Wv/Wp casts + g2(+SCALE) + G via fp32 VALU
//    (no MFMA latency trap, no transposes, no split-K/reduce). 8 dispatches total.
//  - w[j] folded into S-gemm epilogue; softmax is plain.
//  - gemm_core64: BK=64 (32KB LDS, still 3 blocks/CU), half the barriers/drains.
//    XOR chunk swizzle phys = g ^ (row&7): glds writes lane-linear, reads 2-way max.

#define BB 16
#define CC 512
#define LL 1024
#define SCALE 0.04419417382415922f

typedef __bf16 bf16x8 __attribute__((ext_vector_type(8)));
typedef float  f32x4  __attribute__((ext_vector_type(4)));

__device__ inline unsigned short bf16_bits(float f) {
  __hip_bfloat16 h = __float2bfloat16(f);
  return __builtin_bit_cast(unsigned short, h);
}
__device__ inline float bits_lo(unsigned int u) {
  return __builtin_bit_cast(float, u << 16);
}
__device__ inline float bits_hi(unsigned int u) {
  return __builtin_bit_cast(float, u & 0xffff0000u);
}

// ---------------- prep: bn_stats | Wv cast | Wp cast | g2 | G ----------------
// blocks [0,512): bn_stats per channel
// [512,768): Wv -> Avt1 rows 0..511 (bf16)
// [768,1024): Wp -> Wpb (bf16)
// [1024,1026): g2[c] = SCALE * sum_o Wk[o][c]*bq[o]
// [1026,2050): G[a][b] = SCALE * sum_o Wq[o][a]*Wk[o][b] -> Avt1 rows 512..1023
__global__ __launch_bounds__(256) void prep(
    const float* __restrict__ x, const float* __restrict__ gamma,
    const float* __restrict__ beta, const float* __restrict__ Wq,
    const float* __restrict__ bq, const float* __restrict__ Wk,
    const float* __restrict__ Wv, const float* __restrict__ Wp,
    float* __restrict__ scl, float* __restrict__ sft, float* __restrict__ g2,
    __hip_bfloat16* __restrict__ Avt1, __hip_bfloat16* __restrict__ Wpb) {
  int blk = blockIdx.x;
  int t = threadIdx.x;
  if (blk < 512) {
    int c = blk;
    float s = 0.f, s2 = 0.f;
    for (int b = 0; b < BB; ++b) {
      float4 v = ((const float4*)(x + ((size_t)(b * CC + c)) * LL))[t];
      s  += v.x + v.y + v.z + v.w;
      s2 += v.x * v.x + v.y * v.y + v.z * v.z + v.w * v.w;
    }
    for (int m = 32; m; m >>= 1) { s += __shfl_xor(s, m, 64); s2 += __shfl_xor(s2, m, 64); }
    __shared__ float rs[4], rs2[4];
    int wave = t >> 6, lane = t & 63;
    if (lane == 0) { rs[wave] = s; rs2[wave] = s2; }
    __syncthreads();
    if (t == 0) {
      float S  = rs[0] + rs[1] + rs[2] + rs[3];
      float S2 = rs2[0] + rs2[1] + rs2[2] + rs2[3];
      float mean = S * (1.f / 16384.f);
      float var  = S2 * (1.f / 16384.f) - mean * mean;
      float sc = gamma[c] * rsqrtf(var + 1e-5f);
      scl[c] = sc;
      sft[c] = beta[c] - mean * sc;
    }
  } else if (blk < 1024) {
    const float* src = blk < 768 ? Wv : Wp;
    __hip_bfloat16* dst = blk < 768 ? Avt1 : Wpb;
    int i = ((blk & 255) * 256 + t) * 4;
    float4 v = *(const float4*)(src + i);
    ushort4 o;
    o.x = bf16_bits(v.x); o.y = bf16_bits(v.y);
    o.z = bf16_bits(v.z); o.w = bf16_bits(v.w);
    *(ushort4*)(dst + i) = o;
  } else if (blk < 1026) {
    int c = (blk - 1024) * 256 + t;
    float acc = 0.f;
#pragma unroll 8
    for (int o = 0; o < 512; ++o) acc += Wk[(size_t)o * 512 + c] * bq[o];
    g2[c] = acc * SCALE;
  } else {
    int idx = blk - 1026;
    int a = idx >> 1;
    int b = (idx & 1) * 256 + t;
    float acc = 0.f;
#pragma unroll 8
    for (int o = 0; o < 512; ++o)
      acc += Wq[(size_t)o * 512 + a] * Wk[(size_t)o * 512 + b];
    Avt1[262144 + (size_t)a * 512 + b] = __float2bfloat16(acc * SCALE);
  }
}

// ---------------- normalize + transpose: x [B][C][L] -> hnT [B][L][C] bf16 ----
__global__ __launch_bounds__(256) void norm_t(
    const float* __restrict__ x, const float* __restrict__ scl,
    const float* __restrict__ sft, __hip_bfloat16* __restrict__ hnT) {
  __shared__ float tile[32][33];
  int l0 = blockIdx.x * 32, c0 = blockIdx.y * 32, b = blockIdx.z;
  int t = threadIdx.x;
#pragma unroll
  for (int i = 0; i < 4; ++i) {
    int idx = t + i * 256;
    int cc = idx >> 5, ll = idx & 31;
    tile[cc][ll] = x[((size_t)(b * CC + c0 + cc)) * LL + l0 + ll];
  }
  __syncthreads();
#pragma unroll
  for (int i = 0; i < 2; ++i) {
    int idx = t + i * 256;
    int ll = idx >> 4, cc = (idx & 15) * 2;
    float v0 = tile[cc][ll] * scl[c0 + cc] + sft[c0 + cc];
    float v1 = tile[cc + 1][ll] * scl[c0 + cc + 1] + sft[c0 + cc + 1];
    ushort2 o; o.x = bf16_bits(v0); o.y = bf16_bits(v1);
    *(ushort2*)(hnT + ((size_t)(b * LL + l0 + ll)) * CC + c0 + cc) = o;
  }
}

// ---------------- w GEMV: w[row] = hnT[row]·g2, one row per wave --------------
__global__ __launch_bounds__(256) void w_gemv(
    const __hip_bfloat16* __restrict__ hnT, const float* __restrict__ g2,
    float* __restrict__ w) {
  int wave = threadIdx.x >> 6, lane = threadIdx.x & 63;
  size_t row = (size_t)blockIdx.x * 4 + wave;
  bf16x8 h = *(const bf16x8*)(hnT + row * 512 + lane * 8);
  const float* g = g2 + lane * 8;
  float s = 0.f;
#pragma unroll
  for (int e = 0; e < 8; ++e) s += (float)h[e] * g[e];
  for (int m = 32; m; m >>= 1) s += __shfl_xor(s, m, 64);
  if (lane == 0) w[row] = s;
}

// ---------------- softmax: one row per wave, bf16 in place ----------------
__global__ __launch_bounds__(256) void softmax_bf16(__hip_bfloat16* __restrict__ S) {
  int wave = threadIdx.x >> 6, lane = threadIdx.x & 63;
  size_t row = (size_t)blockIdx.x * 4 + wave;
  uint4* p = (uint4*)(S + row * 1024);
  uint4 r0 = p[lane * 2], r1 = p[lane * 2 + 1];
  float f[16];
  unsigned int ww[8] = {r0.x, r0.y, r0.z, r0.w, r1.x, r1.y, r1.z, r1.w};
#pragma unroll
  for (int i = 0; i < 8; ++i) { f[2 * i] = bits_lo(ww[i]); f[2 * i + 1] = bits_hi(ww[i]); }
  float mx = f[0];
#pragma unroll
  for (int i = 1; i < 16; ++i) mx = fmaxf(mx, f[i]);
  for (int m = 32; m; m >>= 1) mx = fmaxf(mx, __shfl_xor(mx, m, 64));
  float s = 0.f;
#pragma unroll
  for (int i = 0; i < 16; ++i) { f[i] = __expf(f[i] - mx); s += f[i]; }
  for (int m = 32; m; m >>= 1) s += __shfl_xor(s, m, 64);
  float inv = 1.f / s;
  unsigned int ow[8];
#pragma unroll
  for (int i = 0; i < 8; ++i) {
    unsigned int lo = bf16_bits(f[2 * i] * inv);
    unsigned int hi = bf16_bits(f[2 * i + 1] * inv);
    ow[i] = lo | (hi << 16);
  }
  uint4 o0 = {ow[0], ow[1], ow[2], ow[3]}, o1 = {ow[4], ow[5], ow[6], ow[7]};
  p[lane * 2] = o0; p[lane * 2 + 1] = o1;
}

// ---------------- BK=64 GEMM core: acc += A[128xK]*B[128xK]^T -----------------
// LDS per operand 128 rows x 64 bf16 (128B). 8 chunks/row; physical chunk
// slot = global_chunk ^ (row&7). glds: thread t stages row (it*32 + t>>3),
// phys slot t&7 (LDS dest lane-linear), fetching global chunk (t&7)^((t>>3)&7).
// Reads: k-octet g = s*4 + (lane>>4), phys = g ^ (fr&7) -> 2-way max on banks.
__device__ inline void glds(const __hip_bfloat16* g, __hip_bfloat16* l) {
  __builtin_amdgcn_global_load_lds(
      (__attribute__((address_space(1))) void*)(void*)g,
      (__attribute__((address_space(3))) void*)l, 16, 0, 0);
}

__device__ __forceinline__ void gemm_core64(
    const __hip_bfloat16* __restrict__ A, int lda,
    const __hip_bfloat16* __restrict__ B, int ldb, int K,
    __hip_bfloat16* sA, __hip_bfloat16* sB, f32x4 (&acc)[4][4]) {
  const int tid = threadIdx.x;
  const int wave = tid >> 6, lane = tid & 63;
  const int wm = (wave >> 1) * 64, wn = (wave & 1) * 64;
  const int row0 = tid >> 3;                       // 0..31
  const int gchunk = ((tid & 7) ^ (row0 & 7)) * 8; // global k-elem offset fetched
  const int fr = lane & 15;
  const int q = lane >> 4;                         // 0..3
  for (int k0 = 0; k0 < K; k0 += 64) {
    __syncthreads();
#pragma unroll
    for (int it = 0; it < 4; ++it) {
      const __hip_bfloat16* ga = A + (size_t)(it * 32 + row0) * lda + k0 + gchunk;
      const __hip_bfloat16* gb = B + (size_t)(it * 32 + row0) * ldb + k0 + gchunk;
      glds(ga, sA + it * 2048 + tid * 8);
      glds(gb, sB + it * 2048 + tid * 8);
    }
    __syncthreads();
#pragma unroll
    for (int s = 0; s < 2; ++s) {
      bf16x8 af[4], bfr[4];
#pragma unroll
      for (int i = 0; i < 4; ++i) {
        int ra = wm + i * 16 + fr;
        af[i] = *(const bf16x8*)(sA + ra * 64 + (((s * 4 + q) ^ (fr & 7)) * 8));
        int rb = wn + i * 16 + fr;
        bfr[i] = *(const bf16x8*)(sB + rb * 64 + (((s * 4 + q) ^ (fr & 7)) * 8));
      }
#pragma unroll
      for (int i = 0; i < 4; ++i)
#pragma unroll
        for (int j = 0; j < 4; ++j)
          acc[i][j] = __builtin_amdgcn_mfma_f32_16x16x32_bf16(af[i], bfr[j], acc[i][j], 0, 0, 0);
    }
  }
}

// ---- fused V/T1: A'=[Wv;G] (1024x512) x hnT -> vN [c][j] natural (+bv),
//      T1T [j][a] packed T-store ----------------------------------------------
__global__ __launch_bounds__(256, 3) void gemm_vt1(
    const __hip_bfloat16* __restrict__ Ap, const __hip_bfloat16* __restrict__ hnT,
    __hip_bfloat16* __restrict__ vN, __hip_bfloat16* __restrict__ T1T,
    const float* __restrict__ bv) {
  __shared__ __align__(16) __hip_bfloat16 sA[128 * 64];
  __shared__ __align__(16) __hip_bfloat16 sB[128 * 64];
  const int bat = blockIdx.z;
  const int m0 = blockIdx.y * 128, n0 = blockIdx.x * 128;
  f32x4 acc[4][4] = {};
  gemm_core64(Ap + (size_t)m0 * 512, 512,
              hnT + (size_t)bat * LL * CC + (size_t)n0 * 512, 512, 512, sA, sB, acc);
  const int lane = threadIdx.x & 63, wave = threadIdx.x >> 6;
  const int wm = (wave >> 1) * 64, wn = (wave & 1) * 64;
  const int crow = (lane >> 4) * 4, ccol = lane & 15;
  const int mloc0 = m0 & 511;
  if (m0 < 512) {
    __hip_bfloat16* D = vN + (size_t)bat * CC * LL;
#pragma unroll
    for (int i = 0; i < 4; ++i) {
      int mg = mloc0 + wm + i * 16 + crow;
      float bv4[4];
#pragma unroll
      for (int r = 0; r < 4; ++r) bv4[r] = bv[mg + r];
#pragma unroll
      for (int j = 0; j < 4; ++j) {
        int ng = n0 + wn + j * 16 + ccol;
#pragma unroll
        for (int r = 0; r < 4; ++r)
          D[(size_t)(mg + r) * 1024 + ng] = __float2bfloat16(acc[i][j][r] + bv4[r]);
      }
    }
  } else {
    __hip_bfloat16* D = T1T + (size_t)bat * LL * CC;
#pragma unroll
    for (int j = 0; j < 4; ++j) {
      int ng = n0 + wn + j * 16 + ccol;
#pragma unroll
      for (int i = 0; i < 4; ++i) {
        int mg = mloc0 + wm + i * 16 + crow;
        ushort4 o;
        o.x = bf16_bits(acc[i][j][0]);
        o.y = bf16_bits(acc[i][j][1]);
        o.z = bf16_bits(acc[i][j][2]);
        o.w = bf16_bits(acc[i][j][3]);
        *(ushort4*)(D + (size_t)ng * 512 + mg) = o;
      }
    }
  }
}

// ---- S GEMM: A=T1T (m=j), B=hnT (n=i), T-store Sb[i][j] + w[j] ---------------
__global__ __launch_bounds__(256, 3) void gemm_sw(
    const __hip_bfloat16* __restrict__ T1T, const __hip_bfloat16* __restrict__ hnT,
    __hip_bfloat16* __restrict__ Sb, const float* __restrict__ w) {
  __shared__ __align__(16) __hip_bfloat16 sA[128 * 64];
  __shared__ __align__(16) __hip_bfloat16 sB[128 * 64];
  const int bat = blockIdx.z;
  const int m0 = blockIdx.y * 128, n0 = blockIdx.x * 128;
  const size_t sLC = (size_t)LL * CC;
  f32x4 acc[4][4] = {};
  gemm_core64(T1T + (size_t)bat * sLC + (size_t)m0 * 512, 512,
              hnT + (size_t)bat * sLC + (size_t)n0 * 512, 512, 512, sA, sB, acc);
  const int lane = threadIdx.x & 63, wave = threadIdx.x >> 6;
  const int wm = (wave >> 1) * 64, wn = (wave & 1) * 64;
  const int crow = (lane >> 4) * 4, ccol = lane & 15;
  __hip_bfloat16* Db = Sb + (size_t)bat * LL * LL;
  const float* wb = w + (size_t)bat * LL;
#pragma unroll
  for (int j = 0; j < 4; ++j) {
    int ng = n0 + wn + j * 16 + ccol;
#pragma unroll
    for (int i = 0; i < 4; ++i) {
      int mg = m0 + wm + i * 16 + crow;
      float4 wv4 = *(const float4*)(wb + mg);
      ushort4 o;
      o.x = bf16_bits(acc[i][j][0] + wv4.x);
      o.y = bf16_bits(acc[i][j][1] + wv4.y);
      o.z = bf16_bits(acc[i][j][2] + wv4.z);
      o.w = bf16_bits(acc[i][j][3] + wv4.w);
      *(ushort4*)(Db + (size_t)ng * 1024 + mg) = o;
    }
  }
}

// ---- PV: A=vN (m=c), B=Sb=P (n=i), K=1024, T-store HT[i][c] ------------------
__global__ __launch_bounds__(256, 3) void gemm_pv(
    const __hip_bfloat16* __restrict__ vN, const __hip_bfloat16* __restrict__ Sb,
    __hip_bfloat16* __restrict__ HT) {
  __shared__ __align__(16) __hip_bfloat16 sA[128 * 64];
  __shared__ __align__(16) __hip_bfloat16 sB[128 * 64];
  const int bat = blockIdx.z;
  const int m0 = blockIdx.y * 128, n0 = blockIdx.x * 128;
  f32x4 acc[4][4] = {};
  gemm_core64(vN + (size_t)bat * CC * LL + (size_t)m0 * 1024, 1024,
              Sb + (size_t)bat * LL * LL + (size_t)n0 * 1024, 1024, 1024, sA, sB, acc);
  const int lane = threadIdx.x & 63, wave = threadIdx.x >> 6;
  const int wm = (wave >> 1) * 64, wn = (wave & 1) * 64;
  const int crow = (lane >> 4) * 4, ccol = lane & 15;
  __hip_bfloat16* Db = HT + (size_t)bat * LL * CC;
#pragma unroll
  for (int j = 0; j < 4; ++j) {
    int ng = n0 + wn + j * 16 + ccol;
#pragma unroll
    for (int i = 0; i < 4; ++i) {
      int mg = m0 + wm + i * 16 + crow;
      ushort4 o;
      o.x = bf16_bits(acc[i][j][0]);
      o.y = bf16_bits(acc[i][j][1]);
      o.z = bf16_bits(acc[i][j][2]);
      o.w = bf16_bits(acc[i][j][3]);
      *(ushort4*)(Db + (size_t)ng * 512 + mg) = o;
    }
  }
}

// ---- proj: A=HT (m=i), B=Wp (n=o), fp32 T-store out[o][i] + bp[o] + x --------
__global__ __launch_bounds__(256, 3) void gemm_f32t(
    const __hip_bfloat16* __restrict__ HT, const __hip_bfloat16* __restrict__ Wpb,
    float* __restrict__ D, const float* __restrict__ bias,
    const float* __restrict__ resid) {
  __shared__ __align__(16) __hip_bfloat16 sA[128 * 64];
  __shared__ __align__(16) __hip_bfloat16 sB[128 * 64];
  const int bat = blockIdx.z;
  const int m0 = blockIdx.y * 128, n0 = blockIdx.x * 128;
  f32x4 acc[4][4] = {};
  gemm_core64(HT + (size_t)bat * LL * CC + (size_t)m0 * 512, 512,
              Wpb + (size_t)n0 * 512, 512, 512, sA, sB, acc);
  const int lane = threadIdx.x & 63, wave = threadIdx.x >> 6;
  const int wm = (wave >> 1) * 64, wn = (wave & 1) * 64;
  const int crow = (lane >> 4) * 4, ccol = lane & 15;
  float* Db = D + (size_t)bat * CC * LL;
  const float* Rb = resid + (size_t)bat * CC * LL;
#pragma unroll
  for (int j = 0; j < 4; ++j) {
    int ng = n0 + wn + j * 16 + ccol;
    float bn = bias[ng];
#pragma unroll
    for (int i = 0; i < 4; ++i) {
      int mg = m0 + wm + i * 16 + crow;
      float4 r = *(const float4*)(Rb + (size_t)ng * 1024 + mg);
      float4 o;
      o.x = acc[i][j][0] + bn + r.x;
      o.y = acc[i][j][1] + bn + r.y;
      o.z = acc[i][j][2] + bn + r.z;
      o.w = acc[i][j][3] + bn + r.w;
      *(float4*)(Db + (size_t)ng * 1024 + mg) = o;
    }
  }
}

extern "C" void kernel_launch(void* const* d_in, const int* in_sizes, int n_in,
                              void* d_out, int out_size, void* d_ws, size_t ws_size,
                              hipStream_t stream) {
  const float* x     = (const float*)d_in[0];
  const float* gamma = (const float*)d_in[1];
  const float* beta  = (const float*)d_in[2];
  const float* Wq    = (const float*)d_in[3];
  const float* bq    = (const float*)d_in[4];
  const float* Wk    = (const float*)d_in[5];
  const float* bk    = (const float*)d_in[6];  // cancels in softmax (row-const)
  const float* Wv    = (const float*)d_in[7];
  const float* bv    = (const float*)d_in[8];
  const float* Wp    = (const float*)d_in[9];
  const float* bp    = (const float*)d_in[10];
  float* out = (float*)d_out;
  (void)bk;

  char* ws = (char*)d_ws;
  float* scl = (float*)ws;                      // 512
  float* sft = scl + 512;                       // 512
  float* g2  = sft + 512;                       // 512 (+512 pad)
  float* w   = g2 + 1024;                       // 16384
  __hip_bfloat16* Avt1 = (__hip_bfloat16*)(w + 16384);  // [Wv;G] 1024x512
  __hip_bfloat16* Wpb  = Avt1 + 524288;         // 512x512
  __hip_bfloat16* hnT  = Wpb + 262144;          // [B][L][C]
  __hip_bfloat16* T1T  = hnT + 8388608;         // [B][L][C]
  __hip_bfloat16* vN   = T1T + 8388608;         // [B][C][L]
  __hip_bfloat16* Sb   = vN + 8388608;          // [B][L][L]
  __hip_bfloat16* HT   = hnT;                   // reuse: hnT dead after S-gemm

  prep<<<2050, 256, 0, stream>>>(x, gamma, beta, Wq, bq, Wk, Wv, Wp,
                                 scl, sft, g2, Avt1, Wpb);
  norm_t<<<dim3(32, 16, 16), 256, 0, stream>>>(x, scl, sft, hnT);
  w_gemv<<<4096, 256, 0, stream>>>(hnT, g2, w);
  gemm_vt1<<<dim3(8, 8, 16), 256, 0, stream>>>(Avt1, hnT, vN, T1T, bv);
  gemm_sw<<<dim3(8, 8, 16), 256, 0, stream>>>(T1T, hnT, Sb, w);
  softmax_bf16<<<4096, 256, 0, stream>>>(Sb);
  gemm_pv<<<dim3(8, 4, 16), 256, 0, stream>>>(vN, Sb, HT);
  gemm_f32t<<<dim3(4, 8, 16), 256, 0, stream>>>(HT, Wpb, out, bp, x);
}